// Round 2
// 280.299 us; speedup vs baseline: 1.0810x; 1.0810x over previous
//
#include <hip/hip_runtime.h>
#include <math.h>

// Problem constants (batch=1024, n=32768), fixed by setup_inputs().
#define NROWS 1024
#define NCOLS 32768
#define NC4   (NCOLS / 4)          // 8192 float4 per row
#define HCOLS (NCOLS / 2)          // columns per scan block (half row)
#define NB_SCAN 2048               // 2 scan blocks per row
#define KCAND 16                   // candidate slots per HALF-row
#define TH_BITS 0xFFFC0000u        // bits >= this  <=>  u >= 1 - 2^-14
// Certified lower bound on -log2f(u) for any screened-OUT element
// (u <= 1-2^-14 -> t >= 8.8055e-5). Guard uses 7.9e-5 (extra 0.9x safety).
#define T_GUARD 7.9e-5f

// Native vector type accepted by __builtin_nontemporal_store (HIP's float4
// is a class type, which the builtin rejects).
typedef float vfloat4 __attribute__((ext_vector_type(4)));

// ---------------------------------------------------------------------------
// Threefry-2x32 with key (0, 42)  == jax.random.key(42) raw key data.
// Exact JAX partitionable scheme (verified bit-exact previously: absmax 0.0).
// ---------------------------------------------------------------------------
__device__ __forceinline__ void tf_round(unsigned &x0, unsigned &x1, int r) {
    x0 += x1;
    x1 = __builtin_rotateleft32(x1, r);   // guarantee v_alignbit_b32
    x1 ^= x0;
}

__device__ __forceinline__ void threefry2x32_key0_42(unsigned &x0, unsigned &x1) {
    const unsigned k0 = 0u;
    const unsigned k1 = 42u;
    const unsigned k2 = 0x1BD11BDAu ^ k0 ^ k1;
    x0 += k0; x1 += k1;
    tf_round(x0, x1, 13); tf_round(x0, x1, 15); tf_round(x0, x1, 26); tf_round(x0, x1, 6);
    x0 += k1; x1 += k2 + 1u;
    tf_round(x0, x1, 17); tf_round(x0, x1, 29); tf_round(x0, x1, 16); tf_round(x0, x1, 24);
    x0 += k2; x1 += k0 + 2u;
    tf_round(x0, x1, 13); tf_round(x0, x1, 15); tf_round(x0, x1, 26); tf_round(x0, x1, 6);
    x0 += k0; x1 += k1 + 3u;
    tf_round(x0, x1, 17); tf_round(x0, x1, 29); tf_round(x0, x1, 16); tf_round(x0, x1, 24);
    x0 += k1; x1 += k2 + 4u;
    tf_round(x0, x1, 13); tf_round(x0, x1, 15); tf_round(x0, x1, 26); tf_round(x0, x1, 6);
    x0 += k2; x1 += k0 + 5u;
}

__device__ __forceinline__ float bits_to_u(unsigned bits) {
    float u = __uint_as_float((bits >> 9) | 0x3f800000u) - 1.0f;
    return fmaxf(u, 1.17549435e-38f);
}

// ---------------------------------------------------------------------------
// kF: role-specialized blocks in ONE launch.
//   - copy blocks (b % stride == 0): pure HBM streaming copy + |x| colsum
//     partials. Never execute threefry -> always have loads in flight.
//   - scan blocks (else): pure threefry candidate scan over a HALF row.
//     Never touch x/out -> pure VALU. Zero their own cnt slot (no memset).
// Interleaved roles guarantee every CU hosts both kinds (m114: memory waves
// and VALU waves on one CU overlap fully). Grid = 8 blocks/CU resident.
// ---------------------------------------------------------------------------
__global__ __launch_bounds__(256) void kF(
        const float4* __restrict__ x4, float4* __restrict__ out4,
        float4* __restrict__ partial4, unsigned* __restrict__ bits0,
        unsigned* __restrict__ cnt, uint2* __restrict__ cand,
        int nrb, int stride) {
    const int b = blockIdx.x;
    const int t = threadIdx.x;

    if (b % stride == 0) {
        // ------------------- copy role -------------------
        const int cid = b / stride;
        const int rpb = NROWS / nrb;
        const int bx = cid & 31, by = cid >> 5;
        const int j4 = bx * 256 + t;
        size_t base = (size_t)(by * rpb) * NC4 + j4;
        float4 acc = make_float4(0.f, 0.f, 0.f, 0.f);
        #pragma unroll 8
        for (int r = 0; r < rpb; ++r) {
            float4 v = x4[base];
            vfloat4 nv = { v.x, v.y, v.z, v.w };
            __builtin_nontemporal_store(nv, (vfloat4*)&out4[base]);  // out never re-read
            acc.x += fabsf(v.x); acc.y += fabsf(v.y);
            acc.z += fabsf(v.z); acc.w += fabsf(v.w);
            base += NC4;
        }
        partial4[(size_t)by * NC4 + j4] = acc;
    } else {
        // ------------------- scan role -------------------
        const int sid = b - b / stride - 1;       // 0 .. NB_SCAN-1
        const int row = sid >> 1, half = sid & 1;
        if (t == 0) cnt[sid] = 0;                 // replaces hipMemsetAsync
        __syncthreads();                          // own-block order: zero before atomics
        const unsigned cbase = (unsigned)row * (unsigned)NCOLS;
        const int jbase = half * HCOLS;
        #pragma unroll 2
        for (int i = 0; i < HCOLS / 256; ++i) {
            const int j = jbase + (i << 8) + t;
            unsigned x0 = 0u, x1 = cbase + (unsigned)j;
            threefry2x32_key0_42(x0, x1);
            const unsigned bits = x0 ^ x1;
            if (j == 0) {
                bits0[row] = bits;
            } else if (bits >= TH_BITS) {
                unsigned pos = atomicAdd(&cnt[sid], 1u);
                if (pos < KCAND) cand[sid * KCAND + pos] = make_uint2((unsigned)j, bits);
            }
        }
    }
}

// ---------------------------------------------------------------------------
// k2: column mean, EMA update, ac = exp(-5*a), w = 1/ac; block sums of ac
// and block mins of w over j>=1. grid 128 x 256. (unchanged)
// ---------------------------------------------------------------------------
__global__ __launch_bounds__(256) void k2_weights(
        const float* __restrict__ partial, const float* __restrict__ activ,
        float* __restrict__ w, float* __restrict__ blocksums,
        float* __restrict__ blockmins, int nrb) {
    const int t = threadIdx.x;
    const int j = blockIdx.x * 256 + t;
    float s = 0.f;
    for (int rb = 0; rb < nrb; ++rb) s += partial[rb * NCOLS + j];
    float m  = s * (1.0f / (float)NROWS);
    float a  = 0.97f * activ[j] + 0.03f * m;     // EMA buffer update
    float ac = expf(-5.0f * a);
    float wj = 1.0f / ac;
    w[j] = wj;
    __shared__ float reds[256];
    __shared__ float redm[256];
    reds[t] = ac;
    redm[t] = (j == 0) ? INFINITY : wj;
    __syncthreads();
    for (int off = 128; off > 0; off >>= 1) {
        if (t < off) {
            reds[t] += reds[t + off];
            redm[t] = fminf(redm[t], redm[t + off]);
        }
        __syncthreads();
    }
    if (t == 0) { blocksums[blockIdx.x] = reds[0]; blockmins[blockIdx.x] = redm[0]; }
}

// ---------------------------------------------------------------------------
// k4: absorbs old k3 (scalar reduction) + winner resolution.
// The 128-entry sum/min trees replicate old k3's association EXACTLY
// (sv[t]=b[t]+b[t+64], then offsets 32..1) so s, w0, wmin are bit-identical
// to the previously-verified kernel. Then per-row: val0 vs <=2x16 candidates
// (two half-row lists); guard falls back to exact full rescan (rare).
// 1024 blocks x 64 threads.
// ---------------------------------------------------------------------------
__global__ __launch_bounds__(64) void k4_resolve(
        const float* __restrict__ w, const float* __restrict__ blocksums,
        const float* __restrict__ blockmins, const unsigned* __restrict__ bits0,
        const unsigned* __restrict__ cnt, const uint2* __restrict__ cand,
        const float* __restrict__ stdp, float* __restrict__ out) {
    const int r = blockIdx.x;
    const int t = threadIdx.x;
    __shared__ float sv[64];
    __shared__ float sm[64];
    __shared__ int   si[64];

    // ---- scalar reduction (bit-exact replica of old k3's tree) ----
    sv[t] = blocksums[t] + blocksums[t + 64];
    sm[t] = fminf(blockmins[t], blockmins[t + 64]);
    __syncthreads();
    for (int off = 32; off > 0; off >>= 1) {
        if (t < off) {
            sv[t] += sv[t + off];
            sm[t] = fminf(sm[t], sm[t + off]);
        }
        __syncthreads();
    }
    const float w0   = 1.0f / (sv[0] * 4000.0f);
    const float wmin = sm[0];

    const float val0 = -__log2f(bits_to_u(bits0[r])) * w0;
    const unsigned c0 = cnt[2 * r];
    const unsigned c1 = cnt[2 * r + 1];
    const bool slow = (c0 > KCAND) || (c1 > KCAND) || !(val0 < T_GUARD * wmin);

    if (!slow) {
        if (t == 0 && (c0 | c1) != 0u) {
            float best = INFINITY;
            int   bi   = 0x7FFFFFFF;
            for (int k = 0; k < (int)c0; ++k) {
                uint2 cd = cand[(2 * r) * KCAND + k];
                float v = -__log2f(bits_to_u(cd.y)) * w[cd.x];
                int   j = (int)cd.x;
                if (v < best || (v == best && j < bi)) { best = v; bi = j; }
            }
            for (int k = 0; k < (int)c1; ++k) {
                uint2 cd = cand[(2 * r + 1) * KCAND + k];
                float v = -__log2f(bits_to_u(cd.y)) * w[cd.x];
                int   j = (int)cd.x;
                if (v < best || (v == best && j < bi)) { best = v; bi = j; }
            }
            if (best < val0 && bi > 0 && bi < NCOLS)
                out[(size_t)r * NCOLS + bi] += stdp[0];
        }
        return;
    }

    // ---- slow path: exact rescan of the whole row ----
    const unsigned cbase = (unsigned)r * (unsigned)NCOLS;
    float best = INFINITY;
    int   bi   = 0x7FFFFFFF;
    for (int j = t; j < NCOLS; j += 64) {
        if (j == 0) continue;
        unsigned x0 = 0u, x1 = cbase + (unsigned)j;
        threefry2x32_key0_42(x0, x1);
        float v = -__log2f(bits_to_u(x0 ^ x1)) * w[j];
        if (v < best) { best = v; bi = j; }
    }
    __syncthreads();                 // sv/sm/si reuse: prior reads complete
    sv[t] = best; si[t] = bi;
    __syncthreads();
    for (int off = 32; off > 0; off >>= 1) {
        if (t < off) {
            float ov = sv[t + off]; int oi = si[t + off];
            if (ov < sv[t] || (ov == sv[t] && oi < si[t])) { sv[t] = ov; si[t] = oi; }
        }
        __syncthreads();
    }
    if (t == 0) {
        if (sv[0] < val0 && si[0] > 0 && si[0] < NCOLS)
            out[(size_t)r * NCOLS + si[0]] += stdp[0];
    }
}

// ---------------------------------------------------------------------------
extern "C" void kernel_launch(void* const* d_in, const int* in_sizes, int n_in,
                              void* d_out, int out_size, void* d_ws, size_t ws_size,
                              hipStream_t stream) {
    (void)in_sizes; (void)n_in; (void)out_size;
    const float* x     = (const float*)d_in[0];   // [1024, 1, 32768] f32
    const float* activ = (const float*)d_in[1];   // [1, 32768] f32
    const float* stdp  = (const float*)d_in[2];   // [1] f32
    float* out = (float*)d_out;                   // [1024, 1, 32768] f32
    char*  ws  = (char*)d_ws;

    // Fixed tail (bytes): w[NCOLS] f32 | blocksums[128] | blockmins[128] |
    // bits0[1024] u32 | cnt[NB_SCAN] u32 | cand[NB_SCAN*KCAND] uint2
    const size_t tail_bytes = (size_t)NCOLS * 4 + 128 * 4 + 128 * 4
                            + NROWS * 4 + (size_t)NB_SCAN * 4
                            + (size_t)NB_SCAN * KCAND * 8;
    int nrb = 16;
    if (ws_size >= (size_t)32 * NCOLS * 4 + tail_bytes) nrb = 32;

    float*    partial   = (float*)ws;
    float*    wbuf      = (float*)(ws + (size_t)nrb * NCOLS * 4);
    float*    blocksums = wbuf + NCOLS;
    float*    blockmins = blocksums + 128;
    unsigned* bits0     = (unsigned*)(blockmins + 128);
    unsigned* cnt       = bits0 + NROWS;
    uint2*    cand      = (uint2*)(cnt + NB_SCAN);

    const int ncopy  = nrb * 32;                  // 1024 (or 512)
    const int stride = (ncopy + NB_SCAN) / ncopy; // 3 (or 5) — coprime with 8 XCDs

    kF<<<ncopy + NB_SCAN, 256, 0, stream>>>((const float4*)x, (float4*)out,
                                            (float4*)partial, bits0, cnt, cand,
                                            nrb, stride);
    k2_weights<<<NCOLS / 256, 256, 0, stream>>>(partial, activ, wbuf,
                                                blocksums, blockmins, nrb);
    k4_resolve<<<NROWS, 64, 0, stream>>>(wbuf, blocksums, blockmins, bits0,
                                         cnt, cand, stdp, out);
}

// Round 4
// 254.767 us; speedup vs baseline: 1.1894x; 1.1002x over previous
//
#include <hip/hip_runtime.h>
#include <math.h>

// Problem constants (batch=1024, n=32768), fixed by setup_inputs().
#define NROWS 1024
#define NCOLS 32768
#define NC4   (NCOLS / 4)          // 8192 float4 per row
#define HCOLS (NCOLS / 2)          // columns per scan block (half row)
#define NB_SCAN 2048               // 2 scan half-rows per row
#define NRB   16                   // row-blocks for colsum partials (64 rows each)
#define KCAND 16                   // candidate slots per HALF-row
#define TH_BITS 0xFFFC0000u        // bits >= this  <=>  u >= 1 - 2^-14
// Certified lower bound on -log2f(u) for any screened-OUT element
// (u <= 1-2^-14 -> t >= 8.8055e-5). Guard uses 7.9e-5 (extra 0.9x safety).
#define T_GUARD 7.9e-5f

// Native vector type accepted by __builtin_nontemporal_store (HIP's float4
// is a class type, which the builtin rejects).
typedef float vfloat4 __attribute__((ext_vector_type(4)));

// ---------------------------------------------------------------------------
// Threefry-2x32 with key (0, 42)  == jax.random.key(42) raw key data.
// Exact JAX partitionable scheme (verified bit-exact previously: absmax 0.0).
// ---------------------------------------------------------------------------
__device__ __forceinline__ void tf_round(unsigned &x0, unsigned &x1, int r) {
    x0 += x1;
    x1 = __builtin_rotateleft32(x1, r);   // v_alignbit_b32
    x1 ^= x0;
}

__device__ __forceinline__ void threefry2x32_key0_42(unsigned &x0, unsigned &x1) {
    const unsigned k0 = 0u;
    const unsigned k1 = 42u;
    const unsigned k2 = 0x1BD11BDAu ^ k0 ^ k1;
    x0 += k0; x1 += k1;
    tf_round(x0, x1, 13); tf_round(x0, x1, 15); tf_round(x0, x1, 26); tf_round(x0, x1, 6);
    x0 += k1; x1 += k2 + 1u;
    tf_round(x0, x1, 17); tf_round(x0, x1, 29); tf_round(x0, x1, 16); tf_round(x0, x1, 24);
    x0 += k2; x1 += k0 + 2u;
    tf_round(x0, x1, 13); tf_round(x0, x1, 15); tf_round(x0, x1, 26); tf_round(x0, x1, 6);
    x0 += k0; x1 += k1 + 3u;
    tf_round(x0, x1, 17); tf_round(x0, x1, 29); tf_round(x0, x1, 16); tf_round(x0, x1, 24);
    x0 += k1; x1 += k2 + 4u;
    tf_round(x0, x1, 13); tf_round(x0, x1, 15); tf_round(x0, x1, 26); tf_round(x0, x1, 6);
    x0 += k2; x1 += k0 + 5u;
}

__device__ __forceinline__ float bits_to_u(unsigned bits) {
    float u = __uint_as_float((bits >> 9) | 0x3f800000u) - 1.0f;
    return fmaxf(u, 1.17549435e-38f);
}

// ---------------------------------------------------------------------------
// kF: WAVE-level role split, single-generation grid.
// 2048 blocks x 256 threads = exactly 8 blocks/CU, all resident, no tail.
// Per block: 1 copy wave (id rotated by b&3 to spread across SIMDs) +
// 3 scan waves. Per CU steady state: 8 copy waves (64KB loads in flight)
// + 24 scan waves (6/SIMD of pure VALU). m114: the pipes overlap fully.
//   copy wave  : 64 float4-cols x 64 rows stream copy + |x| colsum partial.
//   scan waves : 192 lanes jointly stride one HALF row (16384 cols) of
//                threefry candidate screening; unroll 4 -> 4 indep chains.
// Block b also owns candidate list sid=b (row=b>>1, half=b&1), zeroing its
// own cnt slot (no memset dispatch).
// ---------------------------------------------------------------------------
__global__ __launch_bounds__(256, 8) void kF(
        const float4* __restrict__ x4, float4* __restrict__ out4,
        float4* __restrict__ partial4, unsigned* __restrict__ bits0,
        unsigned* __restrict__ cnt, uint2* __restrict__ cand) {
    const int b    = blockIdx.x;
    const int t    = threadIdx.x;
    const int wid  = t >> 6;
    const int lane = t & 63;

    if (t == 0) cnt[b] = 0;        // own candidate-counter slot
    __syncthreads();               // zero visible before scan atomics

    const int copy_wid = b & 3;    // rotate copy wave across SIMDs

    if (wid == copy_wid) {
        // ------------------- copy role (1 wave) -------------------
        // wave b copies col-group (b&127)*64 x row-group (b>>7)*64.
        const int colg = b & 127;          // 128 groups x 64 float4 = 8192
        const int rowg = b >> 7;           // 16 groups x 64 rows = 1024
        const int j4   = colg * 64 + lane; // lane-consecutive -> coalesced 1KB
        size_t base = (size_t)(rowg * 64) * NC4 + j4;
        float4 acc = make_float4(0.f, 0.f, 0.f, 0.f);
        #pragma unroll 8
        for (int r = 0; r < 64; ++r) {
            float4 v = x4[base];
            vfloat4 nv = { v.x, v.y, v.z, v.w };
            __builtin_nontemporal_store(nv, (vfloat4*)&out4[base]);  // out never re-read
            acc.x += fabsf(v.x); acc.y += fabsf(v.y);
            acc.z += fabsf(v.z); acc.w += fabsf(v.w);
            base += NC4;
        }
        partial4[(size_t)rowg * NC4 + j4] = acc;   // NRB=16 row-blocks
    } else {
        // ------------------- scan role (3 waves) -------------------
        const int row  = b >> 1, half = b & 1;
        const int swid = wid - (wid > copy_wid ? 1 : 0);  // 0..2
        const int sl   = swid * 64 + lane;                // 0..191
        const unsigned cbase = (unsigned)row * (unsigned)NCOLS;
        const int jbase = half * HCOLS;
        // lanes of one wave share trip count (86/85/85) -> no divergence
        #pragma unroll 4
        for (int i = sl; i < HCOLS; i += 192) {
            const int j = jbase + i;
            unsigned x0 = 0u, x1 = cbase + (unsigned)j;
            threefry2x32_key0_42(x0, x1);
            const unsigned bits = x0 ^ x1;
            if (j == 0) {
                bits0[row] = bits;
            } else if (bits >= TH_BITS) {
                unsigned pos = atomicAdd(&cnt[b], 1u);
                if (pos < KCAND) cand[b * KCAND + pos] = make_uint2((unsigned)j, bits);
            }
        }
    }
}

// ---------------------------------------------------------------------------
// k2: column mean, EMA update, ac = exp(-5*a), w = 1/ac; block sums of ac
// and block mins of w over j>=1. grid 128 x 256.
// ---------------------------------------------------------------------------
__global__ __launch_bounds__(256) void k2_weights(
        const float* __restrict__ partial, const float* __restrict__ activ,
        float* __restrict__ w, float* __restrict__ blocksums,
        float* __restrict__ blockmins) {
    const int t = threadIdx.x;
    const int j = blockIdx.x * 256 + t;
    float s = 0.f;
    #pragma unroll
    for (int rb = 0; rb < NRB; ++rb) s += partial[rb * NCOLS + j];
    float m  = s * (1.0f / (float)NROWS);
    float a  = 0.97f * activ[j] + 0.03f * m;     // EMA buffer update
    float ac = expf(-5.0f * a);
    float wj = 1.0f / ac;
    w[j] = wj;
    __shared__ float reds[256];
    __shared__ float redm[256];
    reds[t] = ac;
    redm[t] = (j == 0) ? INFINITY : wj;
    __syncthreads();
    for (int off = 128; off > 0; off >>= 1) {
        if (t < off) {
            reds[t] += reds[t + off];
            redm[t] = fminf(redm[t], redm[t + off]);
        }
        __syncthreads();
    }
    if (t == 0) { blocksums[blockIdx.x] = reds[0]; blockmins[blockIdx.x] = redm[0]; }
}

// ---------------------------------------------------------------------------
// k4: scalar reduction (bit-exact replica of the verified k3 tree:
// sv[t]=b[t]+b[t+64], then offsets 32..1) + per-row winner resolution.
// Normal path: val0 vs <=2x16 candidates (two half-row lists); guard falls
// back to exact full rescan (never triggers in practice but guarantees
// correctness). 1024 blocks x 64 threads.
// ---------------------------------------------------------------------------
__global__ __launch_bounds__(64) void k4_resolve(
        const float* __restrict__ w, const float* __restrict__ blocksums,
        const float* __restrict__ blockmins, const unsigned* __restrict__ bits0,
        const unsigned* __restrict__ cnt, const uint2* __restrict__ cand,
        const float* __restrict__ stdp, float* __restrict__ out) {
    const int r = blockIdx.x;
    const int t = threadIdx.x;
    __shared__ float sv[64];
    __shared__ float sm[64];
    __shared__ int   si[64];

    sv[t] = blocksums[t] + blocksums[t + 64];
    sm[t] = fminf(blockmins[t], blockmins[t + 64]);
    __syncthreads();
    for (int off = 32; off > 0; off >>= 1) {
        if (t < off) {
            sv[t] += sv[t + off];
            sm[t] = fminf(sm[t], sm[t + off]);
        }
        __syncthreads();
    }
    const float w0   = 1.0f / (sv[0] * 4000.0f);
    const float wmin = sm[0];

    const float val0 = -__log2f(bits_to_u(bits0[r])) * w0;
    const unsigned c0 = cnt[2 * r];
    const unsigned c1 = cnt[2 * r + 1];
    const bool slow = (c0 > KCAND) || (c1 > KCAND) || !(val0 < T_GUARD * wmin);

    if (!slow) {
        if (t == 0 && (c0 | c1) != 0u) {
            float best = INFINITY;
            int   bi   = 0x7FFFFFFF;
            for (int k = 0; k < (int)c0; ++k) {
                uint2 cd = cand[(2 * r) * KCAND + k];
                float v = -__log2f(bits_to_u(cd.y)) * w[cd.x];
                int   j = (int)cd.x;
                if (v < best || (v == best && j < bi)) { best = v; bi = j; }
            }
            for (int k = 0; k < (int)c1; ++k) {
                uint2 cd = cand[(2 * r + 1) * KCAND + k];
                float v = -__log2f(bits_to_u(cd.y)) * w[cd.x];
                int   j = (int)cd.x;
                if (v < best || (v == best && j < bi)) { best = v; bi = j; }
            }
            if (best < val0 && bi > 0 && bi < NCOLS)
                out[(size_t)r * NCOLS + bi] += stdp[0];
        }
        return;
    }

    // ---- slow path: exact rescan of the whole row ----
    const unsigned cbase = (unsigned)r * (unsigned)NCOLS;
    float best = INFINITY;
    int   bi   = 0x7FFFFFFF;
    for (int j = t; j < NCOLS; j += 64) {
        if (j == 0) continue;
        unsigned x0 = 0u, x1 = cbase + (unsigned)j;
        threefry2x32_key0_42(x0, x1);
        float v = -__log2f(bits_to_u(x0 ^ x1)) * w[j];
        if (v < best) { best = v; bi = j; }
    }
    __syncthreads();                 // sv/si reuse: prior reads complete
    sv[t] = best; si[t] = bi;
    __syncthreads();
    for (int off = 32; off > 0; off >>= 1) {
        if (t < off) {
            float ov = sv[t + off]; int oi = si[t + off];
            if (ov < sv[t] || (ov == sv[t] && oi < si[t])) { sv[t] = ov; si[t] = oi; }
        }
        __syncthreads();
    }
    if (t == 0) {
        if (sv[0] < val0 && si[0] > 0 && si[0] < NCOLS)
            out[(size_t)r * NCOLS + si[0]] += stdp[0];
    }
}

// ---------------------------------------------------------------------------
extern "C" void kernel_launch(void* const* d_in, const int* in_sizes, int n_in,
                              void* d_out, int out_size, void* d_ws, size_t ws_size,
                              hipStream_t stream) {
    (void)in_sizes; (void)n_in; (void)out_size; (void)ws_size;
    const float* x     = (const float*)d_in[0];   // [1024, 1, 32768] f32
    const float* activ = (const float*)d_in[1];   // [1, 32768] f32
    const float* stdp  = (const float*)d_in[2];   // [1] f32
    float* out = (float*)d_out;                   // [1024, 1, 32768] f32
    char*  ws  = (char*)d_ws;

    // ws layout: partial[NRB*NCOLS] f32 | w[NCOLS] f32 | blocksums[128] |
    // blockmins[128] | bits0[1024] u32 | cnt[NB_SCAN] u32 | cand[NB_SCAN*KCAND]
    float*    partial   = (float*)ws;
    float*    wbuf      = partial + (size_t)NRB * NCOLS;
    float*    blocksums = wbuf + NCOLS;
    float*    blockmins = blocksums + 128;
    unsigned* bits0     = (unsigned*)(blockmins + 128);
    unsigned* cnt       = bits0 + NROWS;
    uint2*    cand      = (uint2*)(cnt + NB_SCAN);

    kF<<<NB_SCAN, 256, 0, stream>>>((const float4*)x, (float4*)out,
                                    (float4*)partial, bits0, cnt, cand);
    k2_weights<<<NCOLS / 256, 256, 0, stream>>>(partial, activ, wbuf,
                                                blocksums, blockmins);
    k4_resolve<<<NROWS, 64, 0, stream>>>(wbuf, blocksums, blockmins, bits0,
                                         cnt, cand, stdp, out);
}